// Round 13
// baseline (116.917 us; speedup 1.0000x reference)
//
#include <hip/hip_runtime.h>
#include <hip/hip_bf16.h>

typedef __attribute__((ext_vector_type(8))) short short8;
typedef __attribute__((ext_vector_type(4))) float f32x4;
typedef __attribute__((ext_vector_type(8))) unsigned short ushort8;
typedef __attribute__((ext_vector_type(4))) unsigned short ushort4v;

__device__ __forceinline__ float bf2f(unsigned short u) {
  union { unsigned int i; float f; } v;
  v.i = ((unsigned int)u) << 16;
  return v.f;
}

__device__ __forceinline__ unsigned short f2bf(float f) {
  union { float f; unsigned int i; } v;
  v.f = f;
  unsigned int x = v.i;
  return (unsigned short)((x + 0x7FFFu + ((x >> 16) & 1u)) >> 16);
}

__device__ __forceinline__ void async_load16(const void* g, void* l) {
  __builtin_amdgcn_global_load_lds(
      (const __attribute__((address_space(1))) unsigned int*)g,
      (__attribute__((address_space(3))) unsigned int*)l, 16, 0, 0);
}

// ---------------------------------------------------------------------------
// Kernel 1: conversions (unchanged champion).
// ---------------------------------------------------------------------------
__global__ __launch_bounds__(256) void cvt_all(
    const float* __restrict__ fc1, unsigned short* __restrict__ fc1b,
    const float* __restrict__ w2, unsigned short* __restrict__ w2b) {
  __shared__ float row[2304];
  const int bx = blockIdx.x;
  const int tid = threadIdx.x;
  if (bx < 1024) {
    const float* src = fc1 + (size_t)bx * 2304;
    for (int i = tid; i < 2304; i += 256) row[i] = src[i];
    __syncthreads();
    unsigned short* dst = fc1b + (size_t)bx * 2304;
    for (int i = tid; i < 2304; i += 256) {
      int pp = i >> 6, c2 = i & 63;
      dst[i] = f2bf(row[c2 * 36 + pp]);
    }
  } else {
    const int p = bx - 1024;  // 0..35
    for (int i = tid; i < 3072; i += 256) {
      int c2 = i / 48, kk = i - c2 * 48;
      w2b[(size_t)p * 3072 + i] = f2bf(w2[(size_t)c2 * 1728 + p * 48 + kk]);
    }
  }
}

// ---------------------------------------------------------------------------
// Kernel 2: fused conv1+conv2 (unchanged champion, u2-loop x-slab reuse).
// ---------------------------------------------------------------------------
#define LDP 72
#define XST 260
__global__ __launch_bounds__(256) void conv_fused6(
    const float* __restrict__ x, const float* __restrict__ w1,
    const unsigned short* __restrict__ w2b, unsigned short* __restrict__ out2,
    int B) {
  __shared__ unsigned short sxb[64 * XST];
  __shared__ unsigned short s_w2[64 * LDP];
  __shared__ unsigned short s_win[64 * LDP];
  const int tid = threadIdx.x;
  const int b0 = blockIdx.x * 64;
  const int u = blockIdx.y;  // 0..5

  {
    int bi = tid >> 2, q = tid & 3;
    ushort4v z = {0, 0, 0, 0};
    *(ushort4v*)&s_win[bi * LDP + 48 + 4 * q] = z;
    *(ushort4v*)&s_w2[bi * LDP + 48 + 4 * q] = z;
  }

  for (int i = tid; i < 3584; i += 256) {
    int bi = i / 56, rem = i - bi * 56;
    int r = rem / 7, c7 = rem - r * 7;
    float4 v = *(const float4*)(x + (size_t)(b0 + bi) * 784 +
                                (4 * u + r) * 28 + c7 * 4);
    ushort4v o;
    o[0] = f2bf(v.x); o[1] = f2bf(v.y); o[2] = f2bf(v.z); o[3] = f2bf(v.w);
    *(ushort4v*)&sxb[bi * XST + r * 32 + c7 * 4] = o;
  }

  const int lane = tid & 63, wave = tid >> 6;
  const int wm = wave >> 1, wn = wave & 1;
  const int fr = lane & 15, fo = (lane >> 4) * 8;

  for (int u2 = 0; u2 < 6; ++u2) {
    const int p = u * 6 + u2;
    __syncthreads();

    {
      const unsigned short* src = w2b + (size_t)p * 3072;
      for (int i = tid; i < 384; i += 256) {
        int c2 = i / 6, q = i - c2 * 6;
        *(ushort8*)&s_w2[c2 * LDP + q * 8] = *(const ushort8*)(src + i * 8);
      }
    }

    for (int it = tid; it < 768; it += 256) {
      int bi = it & 63, cv = it >> 6;
      int c = cv >> 2, v = cv & 3;
      const unsigned short* r0p = &sxb[bi * XST + (2 * v) * 32 + 4 * u2];
      ushort4v a0 = *(const ushort4v*)r0p;
      ushort4v a1 = *(const ushort4v*)(r0p + 4);
      ushort4v b0v = *(const ushort4v*)(r0p + 32);
      ushort4v b1v = *(const ushort4v*)(r0p + 36);
      const float* wbase = w1 + ((c * 196 + (2 * u + v) * 14 + 2 * u2) << 2);
      float4 q0 = *(const float4*)(wbase);
      float4 q1 = *(const float4*)(wbase + 4);
      float4 q2 = *(const float4*)(wbase + 8);
      float4 q3 = *(const float4*)(wbase + 12);
      ushort4v o;
      o[0] = f2bf(fmaxf(bf2f(a0[0]) * q0.x + bf2f(a0[1]) * q0.y +
                        bf2f(b0v[0]) * q0.z + bf2f(b0v[1]) * q0.w, 0.f));
      o[1] = f2bf(fmaxf(bf2f(a0[2]) * q1.x + bf2f(a0[3]) * q1.y +
                        bf2f(b0v[2]) * q1.z + bf2f(b0v[3]) * q1.w, 0.f));
      o[2] = f2bf(fmaxf(bf2f(a1[0]) * q2.x + bf2f(a1[1]) * q2.y +
                        bf2f(b1v[0]) * q2.z + bf2f(b1v[1]) * q2.w, 0.f));
      o[3] = f2bf(fmaxf(bf2f(a1[2]) * q3.x + bf2f(a1[3]) * q3.y +
                        bf2f(b1v[2]) * q3.z + bf2f(b1v[3]) * q3.w, 0.f));
      *(ushort4v*)&s_win[bi * LDP + 4 * cv] = o;
    }
    __syncthreads();

    f32x4 acc[2][2] = {};
    #pragma unroll
    for (int k2 = 0; k2 < 2; ++k2) {
      short8 af[2], bf[2];
      #pragma unroll
      for (int m = 0; m < 2; ++m)
        af[m] = *(const short8*)&s_win[(wm * 32 + m * 16 + fr) * LDP + k2 * 32 + fo];
      #pragma unroll
      for (int n = 0; n < 2; ++n)
        bf[n] = *(const short8*)&s_w2[(wn * 32 + n * 16 + fr) * LDP + k2 * 32 + fo];
      #pragma unroll
      for (int m = 0; m < 2; ++m)
        #pragma unroll
        for (int n = 0; n < 2; ++n)
          acc[m][n] = __builtin_amdgcn_mfma_f32_16x16x32_bf16(af[m], bf[n],
                                                              acc[m][n], 0, 0, 0);
    }
    __syncthreads();

    unsigned short* s_out = s_win;
    const int r0 = wm * 32 + (lane >> 4) * 4;
    const int c0 = wn * 32 + fr;
    #pragma unroll
    for (int m = 0; m < 2; ++m)
      #pragma unroll
      for (int n = 0; n < 2; ++n)
        #pragma unroll
        for (int j = 0; j < 4; ++j)
          s_out[(r0 + m * 16 + j) * 64 + (c0 + n * 16)] =
              f2bf(fmaxf(acc[m][n][j], 0.f));
    __syncthreads();

    for (int it = tid; it < 512; it += 256) {
      int row = it >> 3, ch = it & 7;
      *(short8*)(out2 + (size_t)(b0 + row) * 2304 + p * 64 + ch * 8) =
          *(const short8*)&s_out[row * 64 + ch * 8];
    }
  }
}

// ---------------------------------------------------------------------------
// Kernel 3: 8-phase m201-style GEMM + fused fc2.
// BM=256, BN=128, BK=64, 512 threads (8 waves 4x2, 64x64 out per wave),
// grid (32,8) = 256 blocks = 1/CU, 2 waves/SIMD.  Triple-buffered K-tiles,
// 4 phases/tile x {6 ds_read || staging slice -> barrier -> lgkmcnt(0) ->
// setprio -> 8 MFMA -> setprio -> barrier}, vmcnt(6) once per tile (2 tiles
// + 6 loads always in flight), T2 source-side XOR swizzle.
// ---------------------------------------------------------------------------
#define GBM 256
#define GBN 128
#define GBK 64
#define ASZ (GBM * GBK)  // 16384 ushorts
#define BSZ (GBN * GBK)  // 8192 ushorts

__global__ __launch_bounds__(512) void gemm8p(
    const unsigned short* __restrict__ A,   // [M][K] out2 bf16 (k' order)
    const unsigned short* __restrict__ Bw,  // [N][K] fc1b bf16 (k' order)
    const float* __restrict__ Wfc2,         // [10][1024] f32
    float* __restrict__ out,                // [M][10] f32 (pre-zeroed)
    int K, int NT) {
  __shared__ unsigned short smem[3 * (ASZ + BSZ)];  // 144 KiB
  __shared__ float sW[10 * GBN];                    // 5 KiB
  const int tid = threadIdx.x;
  const int lane = tid & 63;
  const int wave = tid >> 6;
  const int wm = wave >> 1, wn = wave & 1;  // 4 x 2 wave grid, 64x64 each
  const size_t m0 = (size_t)blockIdx.x * GBM;
  const size_t n0 = (size_t)blockIdx.y * GBN;

  // staging geometry: 64 rows/round, 8 chunks of 8 elems, T2 source swizzle
  const int r8 = tid >> 3;
  const int c8 = tid & 7;
  const int ksw = (c8 ^ (r8 & 7)) * 8;
  const unsigned short* Ag = A + (m0 + r8) * (size_t)K + ksw;
  const unsigned short* Bg = Bw + (n0 + r8) * (size_t)K + ksw;
  const int dst = r8 * GBK + c8 * 8;

#define STG_A(buf, t, i) \
  async_load16(Ag + (size_t)(t) * GBK + (size_t)(i) * 64 * K, \
               smem + (buf) * ASZ + (i) * 4096 + dst)
#define STG_B(buf, t, i) \
  async_load16(Bg + (size_t)(t) * GBK + (size_t)(i) * 64 * K, \
               smem + 3 * ASZ + (buf) * BSZ + (i) * 4096 + dst)

  // prologue: tiles 0 and 1 fully in flight (6 loads each)
  STG_A(0, 0, 0); STG_A(0, 0, 1); STG_A(0, 0, 2); STG_A(0, 0, 3);
  STG_B(0, 0, 0); STG_B(0, 0, 1);
  STG_A(1, 1, 0); STG_A(1, 1, 1); STG_A(1, 1, 2); STG_A(1, 1, 3);
  STG_B(1, 1, 0); STG_B(1, 1, 1);

  // fragment read geometry
  const int fr = lane & 15, fg = lane >> 4, fx = lane & 7;
  const int jc0 = (fg ^ fx) * 8;
  int aOff[4], bOff[4];
  #pragma unroll
  for (int m = 0; m < 4; ++m) aOff[m] = (wm * 64 + m * 16 + fr) * GBK + jc0;
  #pragma unroll
  for (int n = 0; n < 4; ++n) bOff[n] = (wn * 64 + n * 16 + fr) * GBK + jc0;

  asm volatile("s_waitcnt vmcnt(6)" ::: "memory");  // tile 0 landed
  __builtin_amdgcn_s_barrier();

  f32x4 acc[4][4] = {};

  for (int t = 0; t < NT; ++t) {
    const int cb = t - (t / 3) * 3;
    const unsigned short* As = smem + cb * ASZ;
    const unsigned short* Bs = smem + 3 * ASZ + cb * BSZ;
    const int t2 = t + 2;
    const int sb = t2 - (t2 / 3) * 3;
    const bool st = t2 < NT;
    short8 af[4], bq[2];

    // ---- phase 0: ks=0, n=0,1 ----
    #pragma unroll
    for (int m = 0; m < 4; ++m) af[m] = *(const short8*)&As[aOff[m]];
    bq[0] = *(const short8*)&Bs[bOff[0]];
    bq[1] = *(const short8*)&Bs[bOff[1]];
    if (st) { STG_A(sb, t2, 0); STG_A(sb, t2, 1); }
    __builtin_amdgcn_s_barrier();
    asm volatile("s_waitcnt lgkmcnt(0)" ::: "memory");
    __builtin_amdgcn_s_setprio(1);
    #pragma unroll
    for (int m = 0; m < 4; ++m)
      acc[m][0] = __builtin_amdgcn_mfma_f32_16x16x32_bf16(af[m], bq[0], acc[m][0], 0, 0, 0);
    #pragma unroll
    for (int m = 0; m < 4; ++m)
      acc[m][1] = __builtin_amdgcn_mfma_f32_16x16x32_bf16(af[m], bq[1], acc[m][1], 0, 0, 0);
    __builtin_amdgcn_s_setprio(0);
    __builtin_amdgcn_s_barrier();

    // ---- phase 1: ks=0, n=2,3 ----
    #pragma unroll
    for (int m = 0; m < 4; ++m) af[m] = *(const short8*)&As[aOff[m]];
    bq[0] = *(const short8*)&Bs[bOff[2]];
    bq[1] = *(const short8*)&Bs[bOff[3]];
    if (st) { STG_A(sb, t2, 2); STG_A(sb, t2, 3); }
    __builtin_amdgcn_s_barrier();
    asm volatile("s_waitcnt lgkmcnt(0)" ::: "memory");
    __builtin_amdgcn_s_setprio(1);
    #pragma unroll
    for (int m = 0; m < 4; ++m)
      acc[m][2] = __builtin_amdgcn_mfma_f32_16x16x32_bf16(af[m], bq[0], acc[m][2], 0, 0, 0);
    #pragma unroll
    for (int m = 0; m < 4; ++m)
      acc[m][3] = __builtin_amdgcn_mfma_f32_16x16x32_bf16(af[m], bq[1], acc[m][3], 0, 0, 0);
    __builtin_amdgcn_s_setprio(0);
    __builtin_amdgcn_s_barrier();

    // ---- phase 2: ks=1, n=0,1 ----
    #pragma unroll
    for (int m = 0; m < 4; ++m) af[m] = *(const short8*)&As[aOff[m] ^ 32];
    bq[0] = *(const short8*)&Bs[bOff[0] ^ 32];
    bq[1] = *(const short8*)&Bs[bOff[1] ^ 32];
    if (st) { STG_B(sb, t2, 0); STG_B(sb, t2, 1); }
    __builtin_amdgcn_s_barrier();
    asm volatile("s_waitcnt lgkmcnt(0)" ::: "memory");
    __builtin_amdgcn_s_setprio(1);
    #pragma unroll
    for (int m = 0; m < 4; ++m)
      acc[m][0] = __builtin_amdgcn_mfma_f32_16x16x32_bf16(af[m], bq[0], acc[m][0], 0, 0, 0);
    #pragma unroll
    for (int m = 0; m < 4; ++m)
      acc[m][1] = __builtin_amdgcn_mfma_f32_16x16x32_bf16(af[m], bq[1], acc[m][1], 0, 0, 0);
    __builtin_amdgcn_s_setprio(0);
    __builtin_amdgcn_s_barrier();

    // ---- phase 3: ks=1, n=2,3 (+ tile-boundary counted wait) ----
    #pragma unroll
    for (int m = 0; m < 4; ++m) af[m] = *(const short8*)&As[aOff[m] ^ 32];
    bq[0] = *(const short8*)&Bs[bOff[2] ^ 32];
    bq[1] = *(const short8*)&Bs[bOff[3] ^ 32];
    __builtin_amdgcn_s_barrier();
    asm volatile("s_waitcnt lgkmcnt(0)" ::: "memory");
    __builtin_amdgcn_s_setprio(1);
    #pragma unroll
    for (int m = 0; m < 4; ++m)
      acc[m][2] = __builtin_amdgcn_mfma_f32_16x16x32_bf16(af[m], bq[0], acc[m][2], 0, 0, 0);
    #pragma unroll
    for (int m = 0; m < 4; ++m)
      acc[m][3] = __builtin_amdgcn_mfma_f32_16x16x32_bf16(af[m], bq[1], acc[m][3], 0, 0, 0);
    __builtin_amdgcn_s_setprio(0);
    if (t + 1 < NT) {
      if (t + 1 == NT - 1) {
        asm volatile("s_waitcnt vmcnt(0)" ::: "memory");
      } else {
        asm volatile("s_waitcnt vmcnt(6)" ::: "memory");
      }
    }
    __builtin_amdgcn_s_barrier();
  }
  __syncthreads();  // LDS reads drained; smem reusable

  // ---- stage fc2 weights ----
  for (int i = tid; i < 10 * GBN; i += 512)
    sW[i] = Wfc2[(i >> 7) * 1024 + n0 + (i & 127)];

  // ---- epilogue: relu -> bf16 h-tile into LDS (swizzled), fused fc2 ----
  unsigned short* hs = smem;  // 256*128 ushorts = 64 KiB
  #pragma unroll
  for (int m = 0; m < 4; ++m)
    #pragma unroll
    for (int n = 0; n < 4; ++n)
      #pragma unroll
      for (int j = 0; j < 4; ++j) {
        int row = wm * 64 + m * 16 + fg * 4 + j;  // 0..255
        int col = wn * 64 + n * 16 + fr;          // 0..127
        hs[row * 128 + (col ^ ((row & 7) << 3))] =
            f2bf(fmaxf(acc[m][n][j], 0.f));
      }
  __syncthreads();

  {
    const int row = tid >> 1;   // 0..255
    const int half = tid & 1;   // col half
    const int r7s = (row & 7) << 3;
    float hv[64];
    #pragma unroll
    for (int c = 0; c < 8; ++c) {
      int base = half * 64 + c * 8;
      short8 u = *(const short8*)&hs[row * 128 + (base ^ r7s)];
      #pragma unroll
      for (int q = 0; q < 8; ++q) hv[c * 8 + q] = bf2f((unsigned short)u[q]);
    }
    float* op = out + (m0 + row) * 10;
    #pragma unroll
    for (int o = 0; o < 10; ++o) {
      const float* wr = &sW[o * 128 + half * 64];
      float a = 0.f;
      #pragma unroll
      for (int q = 0; q < 64; ++q) a += hv[q] * wr[q];
      a += __shfl_down(a, 1);
      if (half == 0) atomicAdd(&op[o], a);
    }
  }
#undef STG_A
#undef STG_B
}

// ---------------------------------------------------------------------------
extern "C" void kernel_launch(void* const* d_in, const int* in_sizes, int n_in,
                              void* d_out, int out_size, void* d_ws, size_t ws_size,
                              hipStream_t stream) {
  const float* x   = (const float*)d_in[0];
  const float* w1  = (const float*)d_in[1];
  const float* w2  = (const float*)d_in[2];
  const float* fc1 = (const float*)d_in[3];
  const float* fc2 = (const float*)d_in[4];
  float* out = (float*)d_out;
  const int B = in_sizes[0] / 784;  // 8192

  unsigned short* out2 = (unsigned short*)d_ws;       // B*2304 bf16
  unsigned short* fc1b = out2 + (size_t)B * 2304;     // 1024*2304 bf16
  unsigned short* w2b  = fc1b + (size_t)1024 * 2304;  // 36*64*48 bf16

  hipMemsetAsync(out, 0, (size_t)out_size * sizeof(float), stream);
  cvt_all<<<1060, 256, 0, stream>>>(fc1, fc1b, w2, w2b);
  dim3 cg(B / 64, 6);
  conv_fused6<<<cg, 256, 0, stream>>>(x, w1, w2b, out2, B);
  dim3 g(B / GBM, 1024 / GBN);
  gemm8p<<<g, 512, 0, stream>>>(out2, fc1b, fc2, out, 2304, 2304 / GBK);
}

// Round 14
// 100.899 us; speedup vs baseline: 1.1587x; 1.1587x over previous
//
#include <hip/hip_runtime.h>
#include <hip/hip_bf16.h>

typedef __attribute__((ext_vector_type(8))) short short8;
typedef __attribute__((ext_vector_type(4))) float f32x4;
typedef __attribute__((ext_vector_type(8))) unsigned short ushort8;
typedef __attribute__((ext_vector_type(4))) unsigned short ushort4v;

__device__ __forceinline__ float bf2f(unsigned short u) {
  union { unsigned int i; float f; } v;
  v.i = ((unsigned int)u) << 16;
  return v.f;
}

__device__ __forceinline__ unsigned short f2bf(float f) {
  union { float f; unsigned int i; } v;
  v.f = f;
  unsigned int x = v.i;
  return (unsigned short)((x + 0x7FFFu + ((x >> 16) & 1u)) >> 16);
}

__device__ __forceinline__ void async_load16(const void* g, void* l) {
  __builtin_amdgcn_global_load_lds(
      (const __attribute__((address_space(1))) unsigned int*)g,
      (__attribute__((address_space(3))) unsigned int*)l, 16, 0, 0);
}

// ---------------------------------------------------------------------------
// Kernel 1: conversions.
//   blockIdx.x <  1024 : fc1w f32 -> bf16, k-permuted (k' = p*64 + c2)
//   blockIdx.x >= 1024 : w2 f32 -> bf16, permuted to [p][c2][48] contiguous
// ---------------------------------------------------------------------------
__global__ __launch_bounds__(256) void cvt_all(
    const float* __restrict__ fc1, unsigned short* __restrict__ fc1b,
    const float* __restrict__ w2, unsigned short* __restrict__ w2b) {
  __shared__ float row[2304];
  const int bx = blockIdx.x;
  const int tid = threadIdx.x;
  if (bx < 1024) {
    const float* src = fc1 + (size_t)bx * 2304;
    for (int i = tid; i < 2304; i += 256) row[i] = src[i];
    __syncthreads();
    unsigned short* dst = fc1b + (size_t)bx * 2304;
    for (int i = tid; i < 2304; i += 256) {
      int pp = i >> 6, c2 = i & 63;
      dst[i] = f2bf(row[c2 * 36 + pp]);
    }
  } else {
    const int p = bx - 1024;  // 0..35
    for (int i = tid; i < 3072; i += 256) {
      int c2 = i / 48, kk = i - c2 * 48;
      w2b[(size_t)p * 3072 + i] = f2bf(w2[(size_t)c2 * 1728 + p * 48 + kk]);
    }
  }
}

// ---------------------------------------------------------------------------
// Kernel 2: fused conv1+conv2.  Block = (64 batches, u);  loops u2 = 0..5,
// so the staged x-slab (8 rows) is reused for 6 p-values (p = 6u + u2).
// out2 layout: [B][k'] with k' = p*64 + c2.
// ---------------------------------------------------------------------------
#define LDP 72
#define XST 260  // per-batch LDS stride in ushorts (130 words: 2 lanes/bank)
__global__ __launch_bounds__(256) void conv_fused6(
    const float* __restrict__ x, const float* __restrict__ w1,
    const unsigned short* __restrict__ w2b, unsigned short* __restrict__ out2,
    int B) {
  __shared__ unsigned short sxb[64 * XST];    // 33.3 KiB  x rows bf16
  __shared__ unsigned short s_w2[64 * LDP];   // 9 KiB
  __shared__ unsigned short s_win[64 * LDP];  // 9 KiB
  const int tid = threadIdx.x;
  const int b0 = blockIdx.x * 64;
  const int u = blockIdx.y;  // 0..5

  // --- zero-pad k = 48..63 of both MFMA tiles (only k<48 rewritten later) ---
  {
    int bi = tid >> 2, q = tid & 3;
    ushort4v z = {0, 0, 0, 0};
    *(ushort4v*)&s_win[bi * LDP + 48 + 4 * q] = z;
    *(ushort4v*)&s_w2[bi * LDP + 48 + 4 * q] = z;
  }

  // --- stage x rows 4u..4u+7 (all 28 cols) as bf16, coalesced, ONCE ---
  for (int i = tid; i < 3584; i += 256) {
    int bi = i / 56, rem = i - bi * 56;
    int r = rem / 7, c7 = rem - r * 7;
    float4 v = *(const float4*)(x + (size_t)(b0 + bi) * 784 +
                                (4 * u + r) * 28 + c7 * 4);
    ushort4v o;
    o[0] = f2bf(v.x); o[1] = f2bf(v.y); o[2] = f2bf(v.z); o[3] = f2bf(v.w);
    *(ushort4v*)&sxb[bi * XST + r * 32 + c7 * 4] = o;
  }

  const int lane = tid & 63, wave = tid >> 6;
  const int wm = wave >> 1, wn = wave & 1;
  const int fr = lane & 15, fo = (lane >> 4) * 8;

  for (int u2 = 0; u2 < 6; ++u2) {
    const int p = u * 6 + u2;
    __syncthreads();  // iter 0: x-slab/pad visible; else: prev stores done

    // --- stage w2 slice (contiguous bf16, coalesced ushort8 copy) ---
    {
      const unsigned short* src = w2b + (size_t)p * 3072;
      for (int i = tid; i < 384; i += 256) {
        int c2 = i / 6, q = i - c2 * 6;
        *(ushort8*)&s_w2[c2 * LDP + q * 8] = *(const ushort8*)(src + i * 8);
      }
    }

    // --- win[bi][16c+4v+v2] from LDS x + global w1 (wave-uniform, L1) ---
    for (int it = tid; it < 768; it += 256) {
      int bi = it & 63, cv = it >> 6;
      int c = cv >> 2, v = cv & 3;
      const unsigned short* r0p = &sxb[bi * XST + (2 * v) * 32 + 4 * u2];
      ushort4v a0 = *(const ushort4v*)r0p;
      ushort4v a1 = *(const ushort4v*)(r0p + 4);
      ushort4v b0v = *(const ushort4v*)(r0p + 32);
      ushort4v b1v = *(const ushort4v*)(r0p + 36);
      const float* wbase = w1 + ((c * 196 + (2 * u + v) * 14 + 2 * u2) << 2);
      float4 q0 = *(const float4*)(wbase);
      float4 q1 = *(const float4*)(wbase + 4);
      float4 q2 = *(const float4*)(wbase + 8);
      float4 q3 = *(const float4*)(wbase + 12);
      ushort4v o;
      o[0] = f2bf(fmaxf(bf2f(a0[0]) * q0.x + bf2f(a0[1]) * q0.y +
                        bf2f(b0v[0]) * q0.z + bf2f(b0v[1]) * q0.w, 0.f));
      o[1] = f2bf(fmaxf(bf2f(a0[2]) * q1.x + bf2f(a0[3]) * q1.y +
                        bf2f(b0v[2]) * q1.z + bf2f(b0v[3]) * q1.w, 0.f));
      o[2] = f2bf(fmaxf(bf2f(a1[0]) * q2.x + bf2f(a1[1]) * q2.y +
                        bf2f(b1v[0]) * q2.z + bf2f(b1v[1]) * q2.w, 0.f));
      o[3] = f2bf(fmaxf(bf2f(a1[2]) * q3.x + bf2f(a1[3]) * q3.y +
                        bf2f(b1v[2]) * q3.z + bf2f(b1v[3]) * q3.w, 0.f));
      *(ushort4v*)&s_win[bi * LDP + 4 * cv] = o;
    }
    __syncthreads();  // w2 + win staged

    // --- micro-GEMM: C[bi][c2] = win @ w2^T, 16x16x32 MFMA, waves 2x2 ---
    f32x4 acc[2][2] = {};
    #pragma unroll
    for (int k2 = 0; k2 < 2; ++k2) {
      short8 af[2], bf[2];
      #pragma unroll
      for (int m = 0; m < 2; ++m)
        af[m] = *(const short8*)&s_win[(wm * 32 + m * 16 + fr) * LDP + k2 * 32 + fo];
      #pragma unroll
      for (int n = 0; n < 2; ++n)
        bf[n] = *(const short8*)&s_w2[(wn * 32 + n * 16 + fr) * LDP + k2 * 32 + fo];
      #pragma unroll
      for (int m = 0; m < 2; ++m)
        #pragma unroll
        for (int n = 0; n < 2; ++n)
          acc[m][n] = __builtin_amdgcn_mfma_f32_16x16x32_bf16(af[m], bf[n],
                                                              acc[m][n], 0, 0, 0);
    }
    __syncthreads();  // all frag reads done; s_win reusable as output stage

    // --- restage result, coalesced 16B stores ---
    unsigned short* s_out = s_win;
    const int r0 = wm * 32 + (lane >> 4) * 4;
    const int c0 = wn * 32 + fr;
    #pragma unroll
    for (int m = 0; m < 2; ++m)
      #pragma unroll
      for (int n = 0; n < 2; ++n)
        #pragma unroll
        for (int j = 0; j < 4; ++j)
          s_out[(r0 + m * 16 + j) * 64 + (c0 + n * 16)] =
              f2bf(fmaxf(acc[m][n][j], 0.f));
    __syncthreads();  // restage visible

    for (int it = tid; it < 512; it += 256) {
      int row = it >> 3, ch = it & 7;
      *(short8*)(out2 + (size_t)(b0 + row) * 2304 + p * 64 + ch * 8) =
          *(const short8*)&s_out[row * 64 + ch * 8];
    }
  }
}

// ---------------------------------------------------------------------------
// Kernel 3: fused  h = relu(out2 @ fc1b^T)  and  out += h @ fc2w^T.
// BM=BN=128, BK=64, 512 threads (8 waves 2x4, 64x32 out per wave).
// Double-buffered LDS, counted vmcnt(4), ONE barrier-pair per K-tile,
// T2 source-side XOR swizzle.  (round-6 champion, unchanged)
// ---------------------------------------------------------------------------
#define GBM 128
#define GBN 128
#define GBK 64

__global__ __launch_bounds__(512) void gemm_fc1_fc2(
    const unsigned short* __restrict__ A,   // [M][K] out2 bf16 (k' order)
    const unsigned short* __restrict__ Bw,  // [N][K] fc1b bf16 (k' order)
    const float* __restrict__ Wfc2,         // [10][1024] f32
    float* __restrict__ out,                // [M][10] f32 (pre-zeroed)
    int K, int NT) {
  __shared__ unsigned short sA[2 * GBM * GBK];  // 32 KiB
  __shared__ unsigned short sB[2 * GBN * GBK];  // 32 KiB
  __shared__ float sW[10 * GBN];                // 5 KiB
  const int tid = threadIdx.x;
  const int lane = tid & 63;
  const int wave = tid >> 6;
  const int wm = wave >> 2, wn = wave & 3;  // 2 x 4 wave grid, 64x32 each
  const size_t m0 = (size_t)blockIdx.x * GBM;
  const size_t n0 = (size_t)blockIdx.y * GBN;

  const int r8 = tid >> 3;               // 0..63
  const int c8 = tid & 7;                // 16B chunk 0..7
  const int ksw = (c8 ^ (r8 & 7)) * 8;   // swizzled source k-chunk
  const unsigned short* Ag = A + (m0 + r8) * (size_t)K + ksw;
  const unsigned short* Bg = Bw + (n0 + r8) * (size_t)K + ksw;
  unsigned short* sAp = &sA[r8 * GBK + c8 * 8];
  unsigned short* sBp = &sB[r8 * GBK + c8 * 8];

#define STAGE_A(buf, t, i) \
  async_load16(Ag + (size_t)(t) * GBK + (size_t)(i) * 64 * K, \
               sAp + (buf) * (GBM * GBK) + (i) * 64 * GBK)
#define STAGE_B(buf, t, i) \
  async_load16(Bg + (size_t)(t) * GBK + (size_t)(i) * 64 * K, \
               sBp + (buf) * (GBN * GBK) + (i) * 64 * GBK)
#define STAGE_TILE(buf, t) \
  STAGE_A(buf, t, 0); STAGE_A(buf, t, 1); STAGE_B(buf, t, 0); STAGE_B(buf, t, 1)

  STAGE_TILE(0, 0);

  const int fr = lane & 15, fg = lane >> 4, fx = lane & 7;
  int aBase[4], bBase[2];
  #pragma unroll
  for (int m = 0; m < 4; ++m) aBase[m] = (wm * 64 + m * 16 + fr) * GBK;
  #pragma unroll
  for (int n = 0; n < 2; ++n) bBase[n] = (wn * 32 + n * 16 + fr) * GBK;
  const int jc0 = (fg ^ fx) * 8;
  const int jc1 = jc0 ^ 32;

  f32x4 acc[4][2] = {};

  for (int t = 0; t < NT; ++t) {
    const int cur = t & 1;
    if (t + 1 < NT) {
      STAGE_TILE(cur ^ 1, t + 1);
      asm volatile("s_waitcnt vmcnt(4)" ::: "memory");
    } else {
      asm volatile("s_waitcnt vmcnt(0)" ::: "memory");
    }
    __builtin_amdgcn_s_barrier();

    const unsigned short* As = &sA[cur * GBM * GBK];
    const unsigned short* Bs = &sB[cur * GBN * GBK];
    short8 a0[4], a1[4], b0[2], b1[2];
    #pragma unroll
    for (int m = 0; m < 4; ++m) {
      a0[m] = *(const short8*)&As[aBase[m] + jc0];
      a1[m] = *(const short8*)&As[aBase[m] + jc1];
    }
    #pragma unroll
    for (int n = 0; n < 2; ++n) {
      b0[n] = *(const short8*)&Bs[bBase[n] + jc0];
      b1[n] = *(const short8*)&Bs[bBase[n] + jc1];
    }
    __builtin_amdgcn_s_setprio(1);
    #pragma unroll
    for (int m = 0; m < 4; ++m)
      #pragma unroll
      for (int n = 0; n < 2; ++n)
        acc[m][n] = __builtin_amdgcn_mfma_f32_16x16x32_bf16(a0[m], b0[n],
                                                            acc[m][n], 0, 0, 0);
    #pragma unroll
    for (int m = 0; m < 4; ++m)
      #pragma unroll
      for (int n = 0; n < 2; ++n)
        acc[m][n] = __builtin_amdgcn_mfma_f32_16x16x32_bf16(a1[m], b1[n],
                                                            acc[m][n], 0, 0, 0);
    __builtin_amdgcn_s_setprio(0);
    __builtin_amdgcn_s_barrier();
  }

  for (int i = tid; i < 10 * GBN; i += 512)
    sW[i] = Wfc2[(i >> 7) * 1024 + n0 + (i & 127)];

  unsigned short* hs = sA;
  #pragma unroll
  for (int m = 0; m < 4; ++m)
    #pragma unroll
    for (int n = 0; n < 2; ++n)
      #pragma unroll
      for (int j = 0; j < 4; ++j) {
        int row = wm * 64 + m * 16 + fg * 4 + j;
        int col = wn * 32 + n * 16 + fr;
        hs[row * 128 + (col ^ ((row & 7) << 3))] =
            f2bf(fmaxf(acc[m][n][j], 0.f));
      }
  __syncthreads();

  {
    const int row = tid >> 2;
    const int quar = tid & 3;
    const int r7s = (row & 7) << 3;
    float hv[32];
    #pragma unroll
    for (int c = 0; c < 4; ++c) {
      int base = quar * 32 + c * 8;
      short8 u = *(const short8*)&hs[row * 128 + (base ^ r7s)];
      #pragma unroll
      for (int q = 0; q < 8; ++q) hv[c * 8 + q] = bf2f((unsigned short)u[q]);
    }
    float* op = out + (m0 + row) * 10;
    #pragma unroll
    for (int o = 0; o < 10; ++o) {
      const float* wr = &sW[o * 128 + quar * 32];
      float a = 0.f;
      #pragma unroll
      for (int q = 0; q < 32; ++q) a += hv[q] * wr[q];
      a += __shfl_down(a, 1);
      a += __shfl_down(a, 2);
      if (quar == 0) atomicAdd(&op[o], a);
    }
  }
#undef STAGE_A
#undef STAGE_B
#undef STAGE_TILE
}

// ---------------------------------------------------------------------------
extern "C" void kernel_launch(void* const* d_in, const int* in_sizes, int n_in,
                              void* d_out, int out_size, void* d_ws, size_t ws_size,
                              hipStream_t stream) {
  const float* x   = (const float*)d_in[0];
  const float* w1  = (const float*)d_in[1];
  const float* w2  = (const float*)d_in[2];
  const float* fc1 = (const float*)d_in[3];
  const float* fc2 = (const float*)d_in[4];
  float* out = (float*)d_out;
  const int B = in_sizes[0] / 784;  // 8192

  unsigned short* out2 = (unsigned short*)d_ws;       // B*2304 bf16
  unsigned short* fc1b = out2 + (size_t)B * 2304;     // 1024*2304 bf16
  unsigned short* w2b  = fc1b + (size_t)1024 * 2304;  // 36*64*48 bf16

  hipMemsetAsync(out, 0, (size_t)out_size * sizeof(float), stream);
  cvt_all<<<1060, 256, 0, stream>>>(fc1, fc1b, w2, w2b);
  dim3 cg(B / 64, 6);
  conv_fused6<<<cg, 256, 0, stream>>>(x, w1, w2b, out2, B);
  dim3 g(B / GBM, 1024 / GBN);
  gemm_fc1_fc2<<<g, 512, 0, stream>>>(out2, fc1b, fc2, out, 2304, 2304 / GBK);
}